// Round 11
// baseline (3253.434 us; speedup 1.0000x reference)
//
#include <hip/hip_runtime.h>

#define HID 1024
#define G4 4096
#define TCH 128
#define NCH 4
#define NWG 256

typedef short short8 __attribute__((ext_vector_type(8)));
typedef float f32x4 __attribute__((ext_vector_type(4)));
typedef unsigned int u32x4 __attribute__((ext_vector_type(4)));

static __device__ __forceinline__ unsigned short f2bf(float f) {
    unsigned int u = __builtin_bit_cast(unsigned int, f);
    u += 0x7fffu + ((u >> 16) & 1u);
    return (unsigned short)(u >> 16);
}
static __device__ __forceinline__ unsigned short f2h(float v) {
    _Float16 h = (_Float16)v;
    return __builtin_bit_cast(unsigned short, h);
}
static __device__ __forceinline__ float h2f(unsigned short u) {
    return (float)__builtin_bit_cast(_Float16, u);
}

// fp32 -> bf16 bulk convert (n8 groups of 8)
__global__ void cvt_mat(const float* __restrict__ src, unsigned short* __restrict__ dst, int n8) {
    int idx = blockIdx.x * blockDim.x + threadIdx.x;
    if (idx >= n8) return;
    const float* s = src + (size_t)idx * 8;
    float4 a = *(const float4*)s;
    float4 b = *(const float4*)(s + 4);
    short8 v;
    v[0]=(short)f2bf(a.x); v[1]=(short)f2bf(a.y); v[2]=(short)f2bf(a.z); v[3]=(short)f2bf(a.w);
    v[4]=(short)f2bf(b.x); v[5]=(short)f2bf(b.y); v[6]=(short)f2bf(b.z); v[7]=(short)f2bf(b.w);
    *(short8*)(dst + (size_t)idx * 8) = v;
}

// zero state region (hcan, cws, hx), combine biases, bump per-replay nonce
__global__ void init_kernel(const float* __restrict__ bih, const float* __restrict__ bhh,
                            float* __restrict__ biasc, unsigned int* __restrict__ zbase,
                            int nz, unsigned int* __restrict__ nonce) {
    int i = blockIdx.x * blockDim.x + threadIdx.x;
    if (i < nz) zbase[i] = 0u;
    if (i < G4) biasc[i] = bih[i] + bhh[i];
    if (i == 0) nonce[0] = nonce[0] + 1u;
}

// xg[m][g] = sum_k x_chunk[m][k]*Wih[g][k], m = tl*64 + n; output f16 bits.
__global__ __launch_bounds__(256) void xg_gemm(
    const float* __restrict__ x,            // [64][512][1024] fp32
    const unsigned short* __restrict__ wb,  // Wih_bf [4096][1024]
    unsigned short* __restrict__ xg,        // [TCH*64][4096] f16 chunk
    int t0) {
    __shared__ unsigned short Al[128][72];
    __shared__ unsigned short Bl[128][72];
    const int tid = threadIdx.x, w = tid >> 6, lane = tid & 63;
    const int bm = blockIdx.x >> 5, bn = blockIdx.x & 31;
    const int wr = w >> 1, wc = w & 1;
    const int fr = lane & 15, kg = lane >> 4;
    f32x4 acc[4][4];
    #pragma unroll
    for (int i = 0; i < 4; ++i)
        #pragma unroll
        for (int j = 0; j < 4; ++j) acc[i][j] = (f32x4){0.f,0.f,0.f,0.f};

    for (int kt = 0; kt < 16; ++kt) {
        __syncthreads();
        #pragma unroll
        for (int c = 0; c < 4; ++c) {
            int idx = c * 256 + tid;
            int row = idx >> 3, co = (idx & 7) * 8;
            int m = bm * 128 + row;
            const float* sp = x + ((size_t)(m & 63) * 512 + (size_t)(t0 + (m >> 6))) * 1024
                                + kt * 64 + co;
            float4 a = *(const float4*)sp;
            float4 b = *(const float4*)(sp + 4);
            short8 v;
            v[0]=(short)f2bf(a.x); v[1]=(short)f2bf(a.y); v[2]=(short)f2bf(a.z); v[3]=(short)f2bf(a.w);
            v[4]=(short)f2bf(b.x); v[5]=(short)f2bf(b.y); v[6]=(short)f2bf(b.z); v[7]=(short)f2bf(b.w);
            *(short8*)&Al[row][co] = v;
            *(short8*)&Bl[row][co] = *(const short8*)(wb + (size_t)(bn * 128 + row) * 1024 + kt * 64 + co);
        }
        __syncthreads();
        #pragma unroll
        for (int kb = 0; kb < 2; ++kb) {
            short8 af[4], bf_[4];
            #pragma unroll
            for (int mi = 0; mi < 4; ++mi)
                af[mi] = *(const short8*)&Al[wr*64 + mi*16 + fr][kb*32 + kg*8];
            #pragma unroll
            for (int ni = 0; ni < 4; ++ni)
                bf_[ni] = *(const short8*)&Bl[wc*64 + ni*16 + fr][kb*32 + kg*8];
            #pragma unroll
            for (int mi = 0; mi < 4; ++mi)
                #pragma unroll
                for (int ni = 0; ni < 4; ++ni)
                    acc[mi][ni] = __builtin_amdgcn_mfma_f32_16x16x32_bf16(af[mi], bf_[ni], acc[mi][ni], 0, 0, 0);
        }
    }
    #pragma unroll
    for (int mi = 0; mi < 4; ++mi)
        #pragma unroll
        for (int ni = 0; ni < 4; ++ni)
            #pragma unroll
            for (int r = 0; r < 4; ++r) {
                int row = bm*128 + wr*64 + mi*16 + kg*4 + r;
                int col = bn*128 + wc*64 + ni*16 + fr;
                xg[(size_t)row * 4096 + col] = f2h(acc[mi][ni][r]);
            }
}

// Persistent LSTM chunk (128 steps), TWO interleaved time-streams per group.
// 8 groups x 32 WGs; group G owns batch rows [G*8,+8): stream A = first 4, B = last 4.
// WG owns hidden units [l*32,+32); Whh slice lives in the unified VGPR/AGPR file
// (R10 proved it resident). Substeps alternate A(t), B(t): while B processes, A's
// h-stores propagate through IF$ -> A's next poll hits ready data (RT hidden).
// Transport: tag-in-data u32 {tag16|bf16} via sc0 sc1 (R8-proven); hx store issued
// BEFORE the y HBM store (critical path first). Math is bit-identical to R8/R10.
__global__ __launch_bounds__(512, 2) void lstm_persist(
    const unsigned short* __restrict__ whh,   // Whh_bf [4096][1024]
    const unsigned short* __restrict__ xg,    // [TCH*64][4096] f16 bits
    const float* __restrict__ biasc,          // [4096]
    unsigned short* __restrict__ hcan,        // [64][1024] bf16 chunk-boundary h
    unsigned int* __restrict__ hx,            // [2 strm][2 par][8 G][4][1024] u32 tagged h
    float* __restrict__ cws,                  // [64][1024] chunk-boundary c
    const unsigned int* __restrict__ nonce,   // [1]
    float* __restrict__ y, int t0) {
    __shared__ unsigned short hA[16 * 1024];   // [16][1024] bf16, rows 4..15 zero, swizzled
    __shared__ float sgate[4][2][4][16];
    __shared__ float sbias[4][32];

    const int tid = threadIdx.x, w = tid >> 6, lane = tid & 63;
    const int G = (int)(blockIdx.x >> 5);
    const int l = (int)(blockIdx.x & 31);

    for (int i = tid; i < 12288; i += 512) hA[4096 + i] = 0;   // zero pad rows 4..15
    if (tid < 128) {
        int q = tid >> 5, j = tid & 31;
        sbias[q][j] = biasc[q * 1024 + l * 32 + j];
    }
    const int q = w & 3, hu = w >> 2;
    const int col = lane & 15, kg = lane >> 4;
    const unsigned int nonce6 = nonce[0] & 63u;

    short8 bfr[32];   // Whh rows q*1024 + l*32 + hu*16 + col, K=1024 (AGPR-resident)
    {
        const unsigned short* wp = whh + (size_t)(q * 1024 + l * 32 + hu * 16 + col) * 1024 + kg * 8;
        #pragma unroll
        for (int kb = 0; kb < 32; ++kb) bfr[kb] = *(const short8*)(wp + kb * 32);
    }
    float cA = 0.f, cB = 0.f;   // cell state: pointwise thread owns (n, j) in both streams
    if (tid < 128) {
        int n = tid >> 5, j = tid & 31;
        cA = cws[((size_t)(G * 8 + n) << 10) + l * 32 + j];
        cB = cws[((size_t)(G * 8 + 4 + n) << 10) + l * 32 + j];
    }
    __syncthreads();

    const int sn = w;   // staging row 0..3 (waves 0-3 only)

    for (int s = 0; s < TCH; ++s) {
        const int t = t0 + s;
        #pragma unroll
        for (int strm = 0; strm < 2; ++strm) {
            // ---- xg prefetch (plain loads; complete under the poll/stage) ----
            unsigned short xi = 0, xf = 0, xgv = 0, xo = 0;
            if (tid < 128) {
                int n = tid >> 5, j = tid & 31;
                const unsigned short* xp = xg + ((size_t)(s * 64 + G * 8 + strm * 4 + n) << 12)
                                              + l * 32 + j;
                xi = xp[0]; xf = xp[1024]; xgv = xp[2048]; xo = xp[3072];
            }
            // ---- acquire h_strm(t) + stage (waves 0-3 only; wave sn owns row sn) ----
            if (w < 4) {
                short8 v0, v1;
                if (s == 0) {
                    const unsigned short* hp = hcan + ((size_t)(G * 8 + strm * 4 + sn) << 10)
                                                    + lane * 16;
                    v0 = *(const short8*)hp;
                    v1 = *(const short8*)(hp + 8);
                } else {
                    const unsigned int* pp = hx + (((size_t)(strm * 2 + (t & 1)) * 8 + G) << 12)
                                                + sn * 1024 + lane * 16;
                    const unsigned int ttag = (nonce6 << 10) | ((unsigned)t & 1023u);
                    u32x4 w0, w1, w2, w3;
                    int guard = 0;
                    while (true) {
                        asm volatile("global_load_dwordx4 %0, %1, off sc0 sc1" : "=v"(w0) : "v"(pp)      : "memory");
                        asm volatile("global_load_dwordx4 %0, %1, off sc0 sc1" : "=v"(w1) : "v"(pp + 4)  : "memory");
                        asm volatile("global_load_dwordx4 %0, %1, off sc0 sc1" : "=v"(w2) : "v"(pp + 8)  : "memory");
                        asm volatile("global_load_dwordx4 %0, %1, off sc0 sc1" : "=v"(w3) : "v"(pp + 12) : "memory");
                        asm volatile("s_waitcnt vmcnt(0)"
                                     : "+v"(w0), "+v"(w1), "+v"(w2), "+v"(w3) :: "memory");
                        int ok = 1;
                        #pragma unroll
                        for (int e = 0; e < 4; ++e) {
                            ok &= ((w0[e] >> 16) == ttag);
                            ok &= ((w1[e] >> 16) == ttag);
                            ok &= ((w2[e] >> 16) == ttag);
                            ok &= ((w3[e] >> 16) == ttag);
                        }
                        if (__all(ok) || ++guard > 200000) break;
                    }
                    #pragma unroll
                    for (int e = 0; e < 4; ++e) {
                        v0[e]     = (short)(w0[e] & 0xffffu);
                        v0[4 + e] = (short)(w1[e] & 0xffffu);
                        v1[e]     = (short)(w2[e] & 0xffffu);
                        v1[4 + e] = (short)(w3[e] & 0xffffu);
                    }
                }
                int cg0 = lane * 2;
                char* base = (char*)hA + sn * 2048;
                *(short8*)(base + (((unsigned)(cg0       ^ sn)) << 4)) = v0;
                *(short8*)(base + (((unsigned)((cg0 + 1) ^ sn)) << 4)) = v1;
            }
            __syncthreads();
            // ---- recurrent MFMA: M=16 tile (4 real rows) x N=16 units x K=1024 ----
            f32x4 acc0 = {0.f,0.f,0.f,0.f}, acc1 = {0.f,0.f,0.f,0.f};
            {
                const int row = lane & 15;
                const unsigned rsw = (unsigned)(row & 7);
                const char* base = (const char*)hA + row * 2048;
                #pragma unroll
                for (int kb = 0; kb < 32; kb += 2) {
                    int cgA = kb * 4 + kg;
                    short8 a0 = *(const short8*)(base + (((unsigned)(cgA       ^ rsw)) << 4));
                    short8 a1 = *(const short8*)(base + (((unsigned)((cgA + 4) ^ rsw)) << 4));
                    acc0 = __builtin_amdgcn_mfma_f32_16x16x32_bf16(a0, bfr[kb],     acc0, 0, 0, 0);
                    acc1 = __builtin_amdgcn_mfma_f32_16x16x32_bf16(a1, bfr[kb + 1], acc1, 0, 0, 0);
                }
                #pragma unroll
                for (int r = 0; r < 4; ++r) acc0[r] += acc1[r];
            }
            // C/D: row = kg*4+r -> rows 0..3 live in kg==0; col = lane&15
            if (kg == 0) {
                #pragma unroll
                for (int r = 0; r < 4; ++r)
                    sgate[q][hu][r][col] = acc0[r];
            }
            __syncthreads();
            // ---- pointwise: 128 threads = (row n 0..3, unit j 0..31) ----
            if (tid < 128) {
                int n = tid >> 5, j = tid & 31;
                int ng = G * 8 + strm * 4 + n, jg = l * 32 + j;
                float cr = strm ? cB : cA;
                float iv = sgate[0][j >> 4][n][j & 15] + h2f(xi)  + sbias[0][j];
                float fv = sgate[1][j >> 4][n][j & 15] + h2f(xf)  + sbias[1][j];
                float gv = sgate[2][j >> 4][n][j & 15] + h2f(xgv) + sbias[2][j];
                float ov = sgate[3][j >> 4][n][j & 15] + h2f(xo)  + sbias[3][j];
                iv = 1.f / (1.f + __expf(-iv));
                fv = 1.f / (1.f + __expf(-fv));
                ov = 1.f / (1.f + __expf(-ov));
                float eg = __expf(2.f * gv);
                gv = 1.f - 2.f / (eg + 1.f);
                cr = fv * cr + iv * gv;
                float ec = __expf(2.f * cr);
                float hh = ov * (1.f - 2.f / (ec + 1.f));
                if (strm) cB = cr; else cA = cr;
                unsigned short hb = f2bf(hh);
                if (s == TCH - 1) {
                    hcan[((size_t)ng << 10) + jg] = hb;    // plain: next launch reads it
                    cws[((size_t)ng << 10) + jg] = cr;
                } else {
                    // critical-path store FIRST (hx), y HBM store after
                    unsigned int wv = (((nonce6 << 10) | ((unsigned)(t + 1) & 1023u)) << 16)
                                      | (unsigned int)hb;
                    unsigned int* hp = hx + (((size_t)(strm * 2 + ((t + 1) & 1)) * 8 + G) << 12)
                                          + n * 1024 + jg;
                    asm volatile("global_store_dword %0, %1, off sc0 sc1"
                                 :: "v"(hp), "v"(wv) : "memory");
                }
                y[((size_t)ng << 19) + ((size_t)t << 10) + jg] = hh;
            }
        }
    }
}

extern "C" void kernel_launch(void* const* d_in, const int* in_sizes, int n_in,
                              void* d_out, int out_size, void* d_ws, size_t ws_size,
                              hipStream_t stream) {
    const float* x   = (const float*)d_in[0];
    const float* wih = (const float*)d_in[1];
    const float* whh = (const float*)d_in[2];
    const float* bih = (const float*)d_in[3];
    const float* bhh = (const float*)d_in[4];
    float* y = (float*)d_out;

    char* ws = (char*)d_ws;
    unsigned short* Whh_bf = (unsigned short*)ws;                           // 8 MiB
    unsigned short* Wih_bf = (unsigned short*)(ws + ((size_t)8 << 20));     // 8 MiB
    unsigned short* xgc    = (unsigned short*)(ws + ((size_t)16 << 20));    // 64 MiB (f16)
    char* SB               = ws + ((size_t)80 << 20);
    float* biasc           = (float*)SB;                                    // 16 KiB
    char* zb               = SB + (16u << 10);
    unsigned short* hcan   = (unsigned short*)zb;                           // 128 KiB
    float* cws             = (float*)(zb + (128u << 10));                   // 256 KiB
    unsigned int* hx       = (unsigned int*)(zb + (384u << 10));            // 512 KiB
    unsigned int* nonce    = (unsigned int*)(zb + (896u << 10));            // 4 B (NOT zeroed)
    const int nz = (896 << 10) / 4;
    if (ws_size < ((size_t)81 << 20)) return;

    hipLaunchKernelGGL(cvt_mat, dim3(2048), dim3(256), 0, stream, whh, Whh_bf, G4 * HID / 8);
    hipLaunchKernelGGL(cvt_mat, dim3(2048), dim3(256), 0, stream, wih, Wih_bf, G4 * HID / 8);
    hipLaunchKernelGGL(init_kernel, dim3(896), dim3(256), 0, stream,
                       bih, bhh, biasc, (unsigned int*)zb, nz, nonce);

    for (int chk = 0; chk < NCH; ++chk) {
        int t0 = chk * TCH;
        hipLaunchKernelGGL(xg_gemm, dim3(2048), dim3(256), 0, stream, x, Wih_bf, xgc, t0);
        void* args[] = {(void*)&Whh_bf, (void*)&xgc, (void*)&biasc, (void*)&hcan,
                        (void*)&hx, (void*)&cws, (void*)&nonce, (void*)&y, (void*)&t0};
        hipLaunchCooperativeKernel((const void*)lstm_persist, dim3(NWG), dim3(512),
                                   args, 0, stream);
    }
}

// Round 12
// 2679.647 us; speedup vs baseline: 1.2141x; 1.2141x over previous
//
#include <hip/hip_runtime.h>

#define HID 1024
#define G4 4096
#define TCH 128
#define NCH 4
#define NWG 256

typedef short short8 __attribute__((ext_vector_type(8)));
typedef float f32x4 __attribute__((ext_vector_type(4)));
typedef unsigned int u32x4 __attribute__((ext_vector_type(4)));

static __device__ __forceinline__ unsigned short f2bf(float f) {
    unsigned int u = __builtin_bit_cast(unsigned int, f);
    u += 0x7fffu + ((u >> 16) & 1u);
    return (unsigned short)(u >> 16);
}
static __device__ __forceinline__ unsigned short f2h(float v) {
    _Float16 h = (_Float16)v;
    return __builtin_bit_cast(unsigned short, h);
}
static __device__ __forceinline__ float h2f(unsigned short u) {
    return (float)__builtin_bit_cast(_Float16, u);
}

// fp32 -> bf16 bulk convert (n8 groups of 8)
__global__ void cvt_mat(const float* __restrict__ src, unsigned short* __restrict__ dst, int n8) {
    int idx = blockIdx.x * blockDim.x + threadIdx.x;
    if (idx >= n8) return;
    const float* s = src + (size_t)idx * 8;
    float4 a = *(const float4*)s;
    float4 b = *(const float4*)(s + 4);
    short8 v;
    v[0]=(short)f2bf(a.x); v[1]=(short)f2bf(a.y); v[2]=(short)f2bf(a.z); v[3]=(short)f2bf(a.w);
    v[4]=(short)f2bf(b.x); v[5]=(short)f2bf(b.y); v[6]=(short)f2bf(b.z); v[7]=(short)f2bf(b.w);
    *(short8*)(dst + (size_t)idx * 8) = v;
}

// zero state region (hcan, cws, hx), combine biases, bump per-replay nonce
__global__ void init_kernel(const float* __restrict__ bih, const float* __restrict__ bhh,
                            float* __restrict__ biasc, unsigned int* __restrict__ zbase,
                            int nz, unsigned int* __restrict__ nonce) {
    int i = blockIdx.x * blockDim.x + threadIdx.x;
    if (i < nz) zbase[i] = 0u;
    if (i < G4) biasc[i] = bih[i] + bhh[i];
    if (i == 0) nonce[0] = nonce[0] + 1u;
}

// xg[m][g] = sum_k x_chunk[m][k]*Wih[g][k], m = tl*64 + n; output f16 bits.
__global__ __launch_bounds__(256) void xg_gemm(
    const float* __restrict__ x,            // [64][512][1024] fp32
    const unsigned short* __restrict__ wb,  // Wih_bf [4096][1024]
    unsigned short* __restrict__ xg,        // [TCH*64][4096] f16 chunk
    int t0) {
    __shared__ unsigned short Al[128][72];
    __shared__ unsigned short Bl[128][72];
    const int tid = threadIdx.x, w = tid >> 6, lane = tid & 63;
    const int bm = blockIdx.x >> 5, bn = blockIdx.x & 31;
    const int wr = w >> 1, wc = w & 1;
    const int fr = lane & 15, kg = lane >> 4;
    f32x4 acc[4][4];
    #pragma unroll
    for (int i = 0; i < 4; ++i)
        #pragma unroll
        for (int j = 0; j < 4; ++j) acc[i][j] = (f32x4){0.f,0.f,0.f,0.f};

    for (int kt = 0; kt < 16; ++kt) {
        __syncthreads();
        #pragma unroll
        for (int c = 0; c < 4; ++c) {
            int idx = c * 256 + tid;
            int row = idx >> 3, co = (idx & 7) * 8;
            int m = bm * 128 + row;
            const float* sp = x + ((size_t)(m & 63) * 512 + (size_t)(t0 + (m >> 6))) * 1024
                                + kt * 64 + co;
            float4 a = *(const float4*)sp;
            float4 b = *(const float4*)(sp + 4);
            short8 v;
            v[0]=(short)f2bf(a.x); v[1]=(short)f2bf(a.y); v[2]=(short)f2bf(a.z); v[3]=(short)f2bf(a.w);
            v[4]=(short)f2bf(b.x); v[5]=(short)f2bf(b.y); v[6]=(short)f2bf(b.z); v[7]=(short)f2bf(b.w);
            *(short8*)&Al[row][co] = v;
            *(short8*)&Bl[row][co] = *(const short8*)(wb + (size_t)(bn * 128 + row) * 1024 + kt * 64 + co);
        }
        __syncthreads();
        #pragma unroll
        for (int kb = 0; kb < 2; ++kb) {
            short8 af[4], bf_[4];
            #pragma unroll
            for (int mi = 0; mi < 4; ++mi)
                af[mi] = *(const short8*)&Al[wr*64 + mi*16 + fr][kb*32 + kg*8];
            #pragma unroll
            for (int ni = 0; ni < 4; ++ni)
                bf_[ni] = *(const short8*)&Bl[wc*64 + ni*16 + fr][kb*32 + kg*8];
            #pragma unroll
            for (int mi = 0; mi < 4; ++mi)
                #pragma unroll
                for (int ni = 0; ni < 4; ++ni)
                    acc[mi][ni] = __builtin_amdgcn_mfma_f32_16x16x32_bf16(af[mi], bf_[ni], acc[mi][ni], 0, 0, 0);
        }
    }
    #pragma unroll
    for (int mi = 0; mi < 4; ++mi)
        #pragma unroll
        for (int ni = 0; ni < 4; ++ni)
            #pragma unroll
            for (int r = 0; r < 4; ++r) {
                int row = bm*128 + wr*64 + mi*16 + kg*4 + r;
                int col = bn*128 + wc*64 + ni*16 + fr;
                xg[(size_t)row * 4096 + col] = f2h(acc[mi][ni][r]);
            }
}

// Persistent LSTM chunk (128 steps). 256 WGs x 512 thr. R10 transport (tag-in-data,
// sc0 sc1) with a SHORTER per-step chain:
//  - B-col mapping c -> gate row (c&3)*1024 + l*32 + w*4 + (c>>2): each wave owns
//    4 units x 4 gate types, so i/f/g/o of a (row,unit) live in 4 lanes of ONE wave.
//  - gate gather = 4 __shfl rounds (bijective 4-lane rotation), replacing the sgate
//    LDS tile + second __syncthreads + separate pointwise phase.
//  - hA double-buffered by step parity -> exactly ONE barrier per step.
//  - bias in 4 registers (time-invariant). Math bit-identical to R10.
__global__ __launch_bounds__(512, 2) void lstm_persist(
    const unsigned short* __restrict__ whh,   // Whh_bf [4096][1024]
    const unsigned short* __restrict__ xg,    // [TCH*64][4096] f16 bits
    const float* __restrict__ biasc,          // [4096]
    unsigned short* __restrict__ hcan,        // [64][1024] bf16 chunk-boundary h
    unsigned int* __restrict__ hx,            // [2 par][8 G][8][1024] u32 tagged h
    float* __restrict__ cws,                  // [64][1024] chunk-boundary c
    const unsigned int* __restrict__ nonce,   // [1]
    float* __restrict__ y, int t0) {
    __shared__ unsigned short hA[2][16384];   // [par][16][1024], rows 8..15 zero, swizzled

    const int tid = threadIdx.x, w = tid >> 6, lane = tid & 63;
    const int G = (int)(blockIdx.x >> 5);
    const int l = (int)(blockIdx.x & 31);

    for (int i = tid; i < 8192; i += 512) { hA[0][8192 + i] = 0; hA[1][8192 + i] = 0; }

    const int c  = lane & 15, kg = lane >> 4;
    const int q  = c & 3;                  // gate type of this lane's B column
    const int e  = c >> 2;                 // unit-within-4 of this lane's B column
    const int jg = l * 32 + w * 4 + e;     // global hidden unit (output lanes <32)
    const int nloc = kg * 4 + q;           // group-local batch row (output lanes <32)
    const unsigned int nonce6 = nonce[0] & 63u;

    short8 bfr[32];   // Whh row (q*1024 + jg), K=1024
    {
        const unsigned short* wp = whh + ((size_t)(q * 1024 + jg) << 10) + kg * 8;
        #pragma unroll
        for (int kb = 0; kb < 32; ++kb) bfr[kb] = *(const short8*)(wp + kb * 32);
    }
    const float bi = biasc[jg],        bfv = biasc[1024 + jg];
    const float bg = biasc[2048 + jg], bov = biasc[3072 + jg];

    float creg = 0.f;
    if (lane < 32) creg = cws[((size_t)(G * 8 + nloc) << 10) + jg];
    __syncthreads();

    const int sn = w;   // staging batch row 0..7 (one per wave)

    for (int s = 0; s < TCH; ++s) {
        const int t = t0 + s;
        // ---- xg prefetch (4 scalar loads; complete under the poll) ----
        unsigned short xi = 0, xf = 0, xgv = 0, xo = 0;
        if (lane < 32) {
            const unsigned short* xp = xg + ((size_t)(s * 64 + G * 8 + nloc) << 12) + jg;
            xi = xp[0]; xf = xp[1024]; xgv = xp[2048]; xo = xp[3072];
        }
        // ---- acquire h(t) row sn (poll-with-data), stage into hA[s&1] ----
        short8 v0, v1;
        if (s == 0) {
            const unsigned short* hp = hcan + ((size_t)(G * 8 + sn) << 10) + lane * 16;
            v0 = *(const short8*)hp;
            v1 = *(const short8*)(hp + 8);
        } else {
            const unsigned int* pp = hx + ((size_t)((t & 1) * 8 + G)) * 8192 + sn * 1024 + lane * 16;
            const unsigned int ttag = (nonce6 << 10) | ((unsigned)t & 1023u);
            u32x4 w0, w1, w2, w3;
            int guard = 0;
            while (true) {
                asm volatile("global_load_dwordx4 %0, %1, off sc0 sc1" : "=v"(w0) : "v"(pp)      : "memory");
                asm volatile("global_load_dwordx4 %0, %1, off sc0 sc1" : "=v"(w1) : "v"(pp + 4)  : "memory");
                asm volatile("global_load_dwordx4 %0, %1, off sc0 sc1" : "=v"(w2) : "v"(pp + 8)  : "memory");
                asm volatile("global_load_dwordx4 %0, %1, off sc0 sc1" : "=v"(w3) : "v"(pp + 12) : "memory");
                asm volatile("s_waitcnt vmcnt(0)"
                             : "+v"(w0), "+v"(w1), "+v"(w2), "+v"(w3) :: "memory");
                int ok = 1;
                #pragma unroll
                for (int ee = 0; ee < 4; ++ee) {
                    ok &= ((w0[ee] >> 16) == ttag);
                    ok &= ((w1[ee] >> 16) == ttag);
                    ok &= ((w2[ee] >> 16) == ttag);
                    ok &= ((w3[ee] >> 16) == ttag);
                }
                if (__all(ok) || ++guard > 100000) break;
            }
            #pragma unroll
            for (int ee = 0; ee < 4; ++ee) {
                v0[ee]     = (short)(w0[ee] & 0xffffu);
                v0[4 + ee] = (short)(w1[ee] & 0xffffu);
                v1[ee]     = (short)(w2[ee] & 0xffffu);
                v1[4 + ee] = (short)(w3[ee] & 0xffffu);
            }
        }
        {
            int cg0 = lane * 2;
            char* base = (char*)&hA[s & 1][0] + sn * 2048;
            *(short8*)(base + (((unsigned)(cg0       ^ sn)) << 4)) = v0;
            *(short8*)(base + (((unsigned)((cg0 + 1) ^ sn)) << 4)) = v1;
        }
        __syncthreads();   // the ONLY barrier per step (stage -> MFMA, same parity buffer)

        // ---- recurrent MFMA: M=16 (8 real rows) x N=16 (4 units x 4 gates) x K=1024 ----
        f32x4 acc0 = {0.f,0.f,0.f,0.f}, acc1 = {0.f,0.f,0.f,0.f};
        {
            const int row = lane & 15;
            const unsigned rsw = (unsigned)(row & 7);
            const char* base = (const char*)&hA[s & 1][0] + row * 2048;
            #pragma unroll
            for (int kb = 0; kb < 32; kb += 2) {
                int cgA = kb * 4 + kg;
                short8 a0 = *(const short8*)(base + (((unsigned)(cgA       ^ rsw)) << 4));
                short8 a1 = *(const short8*)(base + (((unsigned)((cgA + 4) ^ rsw)) << 4));
                acc0 = __builtin_amdgcn_mfma_f32_16x16x32_bf16(a0, bfr[kb],     acc0, 0, 0, 0);
                acc1 = __builtin_amdgcn_mfma_f32_16x16x32_bf16(a1, bfr[kb + 1], acc1, 0, 0, 0);
            }
            #pragma unroll
            for (int r = 0; r < 4; ++r) acc0[r] += acc1[r];
        }
        // ---- wave-local gate gather: 4 shuffle rounds (no LDS, no barrier) ----
        // round j: send acc0[(q+j)&3]; pull from lane (lane&~3)|((q-j)&3);
        // received = source's acc0[q_recv] = gate ((q-j)&3) for row nloc.
        float iv = 0.f, fv = 0.f, gv = 0.f, ov = 0.f;
        #pragma unroll
        for (int j = 0; j < 4; ++j) {
            int sel = (q + j) & 3;
            float sv = (sel == 0) ? acc0[0] : (sel == 1) ? acc0[1]
                     : (sel == 2) ? acc0[2] : acc0[3];
            int src = (lane & ~3) | ((q - j) & 3);
            float rv = __shfl(sv, src, 64);
            int g = (q - j) & 3;
            iv = (g == 0) ? rv : iv;
            fv = (g == 1) ? rv : fv;
            gv = (g == 2) ? rv : gv;
            ov = (g == 3) ? rv : ov;
        }
        // ---- pointwise (lanes < 32 hold the 8 real rows x this wave's 4 units) ----
        if (lane < 32) {
            float ivv = iv + h2f(xi)  + bi;
            float fvv = fv + h2f(xf)  + bfv;
            float gvv = gv + h2f(xgv) + bg;
            float ovv = ov + h2f(xo)  + bov;
            ivv = 1.f / (1.f + __expf(-ivv));
            fvv = 1.f / (1.f + __expf(-fvv));
            ovv = 1.f / (1.f + __expf(-ovv));
            float eg = __expf(2.f * gvv);
            gvv = 1.f - 2.f / (eg + 1.f);
            creg = fvv * creg + ivv * gvv;
            float ec = __expf(2.f * creg);
            float hh = ovv * (1.f - 2.f / (ec + 1.f));
            unsigned short hb = f2bf(hh);
            int ng = G * 8 + nloc;
            if (s == TCH - 1) {
                hcan[((size_t)ng << 10) + jg] = hb;    // plain: next launch reads it
                cws[((size_t)ng << 10) + jg] = creg;
            } else {
                unsigned int wv = (((nonce6 << 10) | ((unsigned)(t + 1) & 1023u)) << 16)
                                  | (unsigned int)hb;
                unsigned int* hp = hx + ((size_t)(((t + 1) & 1) * 8 + G)) * 8192
                                      + nloc * 1024 + jg;
                asm volatile("global_store_dword %0, %1, off sc0 sc1"
                             :: "v"(hp), "v"(wv) : "memory");
            }
            y[((size_t)ng << 19) + ((size_t)t << 10) + jg] = hh;
        }
    }
}

extern "C" void kernel_launch(void* const* d_in, const int* in_sizes, int n_in,
                              void* d_out, int out_size, void* d_ws, size_t ws_size,
                              hipStream_t stream) {
    const float* x   = (const float*)d_in[0];
    const float* wih = (const float*)d_in[1];
    const float* whh = (const float*)d_in[2];
    const float* bih = (const float*)d_in[3];
    const float* bhh = (const float*)d_in[4];
    float* y = (float*)d_out;

    char* ws = (char*)d_ws;
    unsigned short* Whh_bf = (unsigned short*)ws;                           // 8 MiB
    unsigned short* Wih_bf = (unsigned short*)(ws + ((size_t)8 << 20));     // 8 MiB
    unsigned short* xgc    = (unsigned short*)(ws + ((size_t)16 << 20));    // 64 MiB (f16)
    char* SB               = ws + ((size_t)80 << 20);
    float* biasc           = (float*)SB;                                    // 16 KiB
    char* zb               = SB + (16u << 10);
    unsigned short* hcan   = (unsigned short*)zb;                           // 128 KiB
    float* cws             = (float*)(zb + (128u << 10));                   // 256 KiB
    unsigned int* hx       = (unsigned int*)(zb + (384u << 10));            // 512 KiB
    unsigned int* nonce    = (unsigned int*)(zb + (896u << 10));            // 4 B (NOT zeroed)
    const int nz = (896 << 10) / 4;
    if (ws_size < ((size_t)81 << 20)) return;

    hipLaunchKernelGGL(cvt_mat, dim3(2048), dim3(256), 0, stream, whh, Whh_bf, G4 * HID / 8);
    hipLaunchKernelGGL(cvt_mat, dim3(2048), dim3(256), 0, stream, wih, Wih_bf, G4 * HID / 8);
    hipLaunchKernelGGL(init_kernel, dim3(896), dim3(256), 0, stream,
                       bih, bhh, biasc, (unsigned int*)zb, nz, nonce);

    for (int chk = 0; chk < NCH; ++chk) {
        int t0 = chk * TCH;
        hipLaunchKernelGGL(xg_gemm, dim3(2048), dim3(256), 0, stream, x, Wih_bf, xgc, t0);
        void* args[] = {(void*)&Whh_bf, (void*)&xgc, (void*)&biasc, (void*)&hcan,
                        (void*)&hx, (void*)&cws, (void*)&nonce, (void*)&y, (void*)&t0};
        hipLaunchCooperativeKernel((const void*)lstm_persist, dim3(NWG), dim3(512),
                                   args, 0, stream);
    }
}